// Round 1
// baseline (18877.397 us; speedup 1.0000x reference)
//
#include <hip/hip_runtime.h>
#include <hip/hip_bf16.h>
#include <math.h>

// ---- problem constants (from reference) ----
#define PATCH   16
#define HIMG    384
#define WIMG    384
#define DMODEL  1024
#define NLAYERS 24
#define DI      2048
#define DSTATE  16
#define DTR     64
#define DC      4
#define LN_EPS  1e-5f
#define BATCH   2
#define GRIDTOK 24                 // 384/16
#define LTOK    (GRIDTOK*GRIDTOK)  // 576
#define NTOK    (BATCH*LTOK)       // 1152
#define KPATCH  (3*PATCH*PATCH)    // 768

__device__ __forceinline__ float sigmoidf_(float v) { return 1.f / (1.f + __expf(-v)); }

// ---------------- im2col for the 16x16/stride-16 patch conv ----------------
__global__ void im2col_kernel(const float* __restrict__ x, float* __restrict__ xcol) {
    int idx = blockIdx.x * blockDim.x + threadIdx.x;
    if (idx >= NTOK * KPATCH) return;
    int t = idx / KPATCH, k = idx % KPATCH;
    int b = t / LTOK, hw = t % LTOK;
    int h = hw / GRIDTOK, w = hw % GRIDTOK;
    int c = k / (PATCH*PATCH), r = k % (PATCH*PATCH);
    int i = r / PATCH, j = r % PATCH;
    xcol[idx] = x[(((size_t)(b*3 + c)*HIMG) + h*PATCH + i)*WIMG + w*PATCH + j];
}

// ---------------- LayerNorm over D=1024, one block per token ----------------
__global__ __launch_bounds__(256) void layernorm_kernel(
        const float* __restrict__ x, const float* __restrict__ g,
        const float* __restrict__ b, float* __restrict__ u) {
    const int t = blockIdx.x;
    const int tid = threadIdx.x;
    const float4 xv = ((const float4*)(x + (size_t)t * DMODEL))[tid];
    float s = xv.x + xv.y + xv.z + xv.w;
    float q = xv.x*xv.x + xv.y*xv.y + xv.z*xv.z + xv.w*xv.w;
    #pragma unroll
    for (int off = 32; off >= 1; off >>= 1) {
        s += __shfl_xor(s, off);
        q += __shfl_xor(q, off);
    }
    __shared__ float red[8];
    if ((tid & 63) == 0) { red[tid >> 6] = s; red[4 + (tid >> 6)] = q; }
    __syncthreads();
    s = red[0] + red[1] + red[2] + red[3];
    q = red[4] + red[5] + red[6] + red[7];
    const float mu   = s * (1.f / DMODEL);
    const float var  = q * (1.f / DMODEL) - mu * mu;
    const float rstd = rsqrtf(var + LN_EPS);
    const float4 gv = ((const float4*)g)[tid];
    const float4 bv = ((const float4*)b)[tid];
    float4 o;
    o.x = (xv.x - mu) * rstd * gv.x + bv.x;
    o.y = (xv.y - mu) * rstd * gv.y + bv.y;
    o.z = (xv.z - mu) * rstd * gv.z + bv.z;
    o.w = (xv.w - mu) * rstd * gv.w + bv.w;
    ((float4*)(u + (size_t)t * DMODEL))[tid] = o;
}

// ---------------- generic fp32 GEMM, C[M,N] = A[M,K] * B[N,K]^T ----------------
// 64x64 tile, K-tile 16, 256 threads, 4x4 micro-tile per thread.
// grid.z > 1 => split-K: each z computes Ksub of K and writes to C + z*M*N.
enum { E_NONE = 0, E_BIAS_POS = 1, E_BIAS_SOFTPLUS = 2, E_RESADD = 3 };

template<int EPI>
__global__ __launch_bounds__(256) void gemm_nt(
        const float* __restrict__ A, int lda,
        const float* __restrict__ B, int ldb,
        float* __restrict__ C, int M, int N, int Ksub,
        const float* __restrict__ bias, const float* __restrict__ aux) {
    __shared__ float As[16][64];
    __shared__ float Bs[16][64];
    const int tid = threadIdx.x;
    const int m0 = blockIdx.x * 64;
    const int n0 = blockIdx.y * 64;
    const int koff = blockIdx.z * Ksub;
    C += (size_t)blockIdx.z * M * N;

    const int lrow = tid >> 2;   // 0..63
    const int kq   = tid & 3;    // 0..3
    const float* aptr = A + (size_t)(m0 + lrow) * lda + koff + kq * 4;
    const bool   bok  = (n0 + lrow) < N;
    const float* bptr = B + (size_t)(n0 + lrow) * ldb + koff + kq * 4;

    float acc[4][4] = {{0.f}};
    for (int k0 = 0; k0 < Ksub; k0 += 16) {
        const float4 av = *(const float4*)(aptr + k0);
        const float4 bv = bok ? *(const float4*)(bptr + k0) : make_float4(0.f, 0.f, 0.f, 0.f);
        __syncthreads();
        As[kq*4+0][lrow] = av.x; As[kq*4+1][lrow] = av.y;
        As[kq*4+2][lrow] = av.z; As[kq*4+3][lrow] = av.w;
        Bs[kq*4+0][lrow] = bv.x; Bs[kq*4+1][lrow] = bv.y;
        Bs[kq*4+2][lrow] = bv.z; Bs[kq*4+3][lrow] = bv.w;
        __syncthreads();
        #pragma unroll
        for (int kk = 0; kk < 16; ++kk) {
            const float4 a = *(const float4*)&As[kk][(tid >> 4) << 2];
            const float4 b = *(const float4*)&Bs[kk][(tid & 15) << 2];
            const float aa[4] = {a.x, a.y, a.z, a.w};
            const float bb[4] = {b.x, b.y, b.z, b.w};
            #pragma unroll
            for (int i = 0; i < 4; ++i)
                #pragma unroll
                for (int j = 0; j < 4; ++j)
                    acc[i][j] = fmaf(aa[i], bb[j], acc[i][j]);
        }
    }

    const int mb = m0 + ((tid >> 4) << 2);
    const int nb = n0 + ((tid & 15) << 2);
    if (nb >= N) return;   // N is a multiple of 4 in all uses; whole float4 in/out
    #pragma unroll
    for (int i = 0; i < 4; ++i) {
        const int m = mb + i;
        float4 v = make_float4(acc[i][0], acc[i][1], acc[i][2], acc[i][3]);
        float* cp = C + (size_t)m * N + nb;
        if (EPI == E_BIAS_POS) {
            const float4 bz = *(const float4*)(bias + nb);
            const float4 pz = *(const float4*)(aux + (size_t)(m % LTOK) * DMODEL + nb);
            v.x += bz.x + pz.x; v.y += bz.y + pz.y; v.z += bz.z + pz.z; v.w += bz.w + pz.w;
        } else if (EPI == E_BIAS_SOFTPLUS) {
            const float4 bz = *(const float4*)(bias + nb);
            v.x += bz.x; v.y += bz.y; v.z += bz.z; v.w += bz.w;
            v.x = (v.x > 20.f) ? v.x : log1pf(__expf(v.x));
            v.y = (v.y > 20.f) ? v.y : log1pf(__expf(v.y));
            v.z = (v.z > 20.f) ? v.z : log1pf(__expf(v.z));
            v.w = (v.w > 20.f) ? v.w : log1pf(__expf(v.w));
        } else if (EPI == E_RESADD) {
            const float4 r = *(const float4*)cp;
            v.x += r.x; v.y += r.y; v.z += r.z; v.w += r.w;
        }
        *(float4*)cp = v;
    }
}

// ---------------- causal depthwise conv1d (DC=4) + silu ----------------
// xi = xz[:, :, 0:DI];  xc[t,e] = silu(sum_k w[e,k]*xi[l+k-3,e] + bc[e])
__global__ void conv1d_silu_kernel(const float* __restrict__ xz,
                                   const float* __restrict__ wc,
                                   const float* __restrict__ bc,
                                   float* __restrict__ xc) {
    int idx = blockIdx.x * blockDim.x + threadIdx.x;
    if (idx >= NTOK * DI) return;
    const int t = idx >> 11;          // DI = 2048
    const int e = idx & (DI - 1);
    const int l = t % LTOK;
    const float4 w = *(const float4*)(wc + e * DC);   // w.x=k0 ... w.w=k3
    const float* xp = xz + (size_t)t * (2*DI) + e;
    float acc = bc[e] + w.w * xp[0];
    if (l >= 1) acc += w.z * xp[-(2*DI)];
    if (l >= 2) acc += w.y * xp[-2*(2*DI)];
    if (l >= 3) acc += w.x * xp[-3*(2*DI)];
    xc[idx] = acc * sigmoidf_(acc);
}

// ---------------- selective scan ----------------
// thread = (b, e, s); 16 lanes per e reduce y = sum_s h_s*C_s via shfl_xor.
// fuses y = (scan + D[e]*xc) * silu(z) epilogue on lane s==0.
__global__ __launch_bounds__(256) void scan_kernel(
        const float* __restrict__ dt, const float* __restrict__ xc,
        const float* __restrict__ dbc, const float* __restrict__ xz,
        const float* __restrict__ Alog, const float* __restrict__ Dp,
        float* __restrict__ y) {
    const int tid = threadIdx.x;
    const int s = tid & 15;
    const int e = blockIdx.x * 16 + (tid >> 4);
    const int b = blockIdx.y;
    const float Aval = -__expf(Alog[e * DSTATE + s]);
    const float Dv = Dp[e];
    const size_t tb = (size_t)b * LTOK;
    const float* dtp = dt  + tb * DI + e;
    const float* xcp = xc  + tb * DI + e;
    const float* bp  = dbc + tb * 96 + 64 + s;   // B block of dbc
    const float* cp  = dbc + tb * 96 + 80 + s;   // C block of dbc
    const float* zp  = xz  + tb * (2*DI) + DI + e;
    float* yp = y + tb * DI + e;
    float h = 0.f;
    #pragma unroll 4
    for (int l = 0; l < LTOK; ++l) {
        const float dtv = dtp[(size_t)l * DI];
        const float xcv = xcp[(size_t)l * DI];
        const float Bv  = bp[l * 96];
        const float Cv  = cp[l * 96];
        const float dA = __expf(dtv * Aval);
        h = fmaf(dA, h, dtv * xcv * Bv);
        float p = h * Cv;
        p += __shfl_xor(p, 1);
        p += __shfl_xor(p, 2);
        p += __shfl_xor(p, 4);
        p += __shfl_xor(p, 8);
        if (s == 0) {
            const float zv = zp[(size_t)l * (2*DI)];
            yp[(size_t)l * DI] = (p + Dv * xcv) * (zv * sigmoidf_(zv));
        }
    }
}

// ---------------- split-K reduce (8 partials) ----------------
__global__ void reduce8_kernel(const float* __restrict__ part, float* __restrict__ out, int n) {
    int i = blockIdx.x * blockDim.x + threadIdx.x;
    if (i >= n) return;
    float s = 0.f;
    #pragma unroll
    for (int z = 0; z < 8; ++z) s += part[(size_t)z * n + i];
    out[i] = s;
}

extern "C" void kernel_launch(void* const* d_in, const int* in_sizes, int n_in,
                              void* d_out, int out_size, void* d_ws, size_t ws_size,
                              hipStream_t stream) {
    const float* x       = (const float*)d_in[0];
    const float* patch_w = (const float*)d_in[1];   // [D, 3,16,16] -> [1024, 768] row-major
    const float* patch_b = (const float*)d_in[2];
    const float* pos     = (const float*)d_in[3];   // [576, 1024]
    const float* ln_g    = (const float*)d_in[4];
    const float* ln_b    = (const float*)d_in[5];
    const float* in_w    = (const float*)d_in[6];   // [L, 4096, 1024]
    const float* conv_w  = (const float*)d_in[7];   // [L, 2048, 4]
    const float* conv_b  = (const float*)d_in[8];
    const float* xproj_w = (const float*)d_in[9];   // [L, 96, 2048]
    const float* dt_w    = (const float*)d_in[10];  // [L, 2048, 64]
    const float* dt_b    = (const float*)d_in[11];
    const float* A_log   = (const float*)d_in[12];  // [L, 2048, 16]
    const float* D_par   = (const float*)d_in[13];
    const float* out_w   = (const float*)d_in[14];  // [L, 1024, 2048]

    float* tok = (float*)d_out;                     // running residual stream [1152, 1024]
    float* ws  = (float*)d_ws;
    float* Xcol = ws;  ws += (size_t)NTOK * KPATCH;      // 884736
    float* u    = ws;  ws += (size_t)NTOK * DMODEL;      // 1179648
    float* xz   = ws;  ws += (size_t)NTOK * 2 * DI;      // 4718592
    float* xc   = ws;  ws += (size_t)NTOK * DI;          // 2359296
    float* dbcP = ws;  ws += (size_t)8 * NTOK * 96;      // 884736
    float* dbc  = ws;  ws += (size_t)NTOK * 96;          // 110592
    float* dtb  = ws;  ws += (size_t)NTOK * DI;          // 2359296
    float* yb   = ws;  ws += (size_t)NTOK * DI;          // 2359296  (~59.4 MB total)

    // ---- patch embed: tok = im2col(x) @ patch_w^T + patch_b + pos ----
    im2col_kernel<<<(NTOK*KPATCH + 255)/256, 256, 0, stream>>>(x, Xcol);
    gemm_nt<E_BIAS_POS><<<dim3(NTOK/64, DMODEL/64), 256, 0, stream>>>(
        Xcol, KPATCH, patch_w, KPATCH, tok, NTOK, DMODEL, KPATCH, patch_b, pos);

    for (int layer = 0; layer < NLAYERS; ++layer) {
        const float* Wg  = ln_g    + (size_t)layer * DMODEL;
        const float* Wb  = ln_b    + (size_t)layer * DMODEL;
        const float* Win = in_w    + (size_t)layer * 2 * DI * DMODEL;
        const float* Wc  = conv_w  + (size_t)layer * DI * DC;
        const float* Bc  = conv_b  + (size_t)layer * DI;
        const float* Wxp = xproj_w + (size_t)layer * 96 * DI;
        const float* Wdt = dt_w    + (size_t)layer * DI * DTR;
        const float* Bdt = dt_b    + (size_t)layer * DI;
        const float* Al  = A_log   + (size_t)layer * DI * DSTATE;
        const float* Dd  = D_par   + (size_t)layer * DI;
        const float* Wo  = out_w   + (size_t)layer * DMODEL * DI;

        // u = LN(tok)
        layernorm_kernel<<<NTOK, 256, 0, stream>>>(tok, Wg, Wb, u);
        // xz = u @ Win^T   [1152, 4096]
        gemm_nt<E_NONE><<<dim3(NTOK/64, (2*DI)/64), 256, 0, stream>>>(
            u, DMODEL, Win, DMODEL, xz, NTOK, 2*DI, DMODEL, nullptr, nullptr);
        // xc = silu(causal_conv(xi) + bc)
        conv1d_silu_kernel<<<(NTOK*DI + 255)/256, 256, 0, stream>>>(xz, Wc, Bc, xc);
        // dbc = xc @ Wxp^T  [1152, 96], split-K=8 for parallelism (deterministic reduce)
        gemm_nt<E_NONE><<<dim3(NTOK/64, 2, 8), 256, 0, stream>>>(
            xc, DI, Wxp, DI, dbcP, NTOK, 96, DI/8, nullptr, nullptr);
        reduce8_kernel<<<(NTOK*96 + 255)/256, 256, 0, stream>>>(dbcP, dbc, NTOK*96);
        // dt = softplus(dbc[:, :64] @ Wdt^T + bdt)  [1152, 2048]
        gemm_nt<E_BIAS_SOFTPLUS><<<dim3(NTOK/64, DI/64), 256, 0, stream>>>(
            dbc, 96, Wdt, DTR, dtb, NTOK, DI, DTR, Bdt, nullptr);
        // selective scan + D*xc + silu(z) gate -> yb
        scan_kernel<<<dim3(DI/16, BATCH), 256, 0, stream>>>(dtb, xc, dbc, xz, Al, Dd, yb);
        // tok += yb @ Wo^T
        gemm_nt<E_RESADD><<<dim3(NTOK/64, DMODEL/64), 256, 0, stream>>>(
            yb, DI, Wo, DI, tok, NTOK, DMODEL, DI, nullptr, nullptr);
    }
}

// Round 2
// 9867.631 us; speedup vs baseline: 1.9131x; 1.9131x over previous
//
#include <hip/hip_runtime.h>
#include <hip/hip_bf16.h>
#include <math.h>

// ---- problem constants (from reference) ----
#define PATCH   16
#define HIMG    384
#define WIMG    384
#define DMODEL  1024
#define NLAYERS 24
#define DI      2048
#define DSTATE  16
#define DTR     64
#define DC      4
#define LN_EPS  1e-5f
#define BATCH   2
#define GRIDTOK 24                 // 384/16
#define LTOK    (GRIDTOK*GRIDTOK)  // 576
#define NTOK    (BATCH*LTOK)       // 1152
#define KPATCH  (3*PATCH*PATCH)    // 768
#define NCH     16                 // scan chunks
#define LC      (LTOK/NCH)         // 36 steps per chunk

__device__ __forceinline__ float sigmoidf_(float v) { return 1.f / (1.f + __expf(-v)); }

// ---------------- im2col for the 16x16/stride-16 patch conv ----------------
__global__ void im2col_kernel(const float* __restrict__ x, float* __restrict__ xcol) {
    int idx = blockIdx.x * blockDim.x + threadIdx.x;
    if (idx >= NTOK * KPATCH) return;
    int t = idx / KPATCH, k = idx % KPATCH;
    int b = t / LTOK, hw = t % LTOK;
    int h = hw / GRIDTOK, w = hw % GRIDTOK;
    int c = k / (PATCH*PATCH), r = k % (PATCH*PATCH);
    int i = r / PATCH, j = r % PATCH;
    xcol[idx] = x[(((size_t)(b*3 + c)*HIMG) + h*PATCH + i)*WIMG + w*PATCH + j];
}

// ---------------- LayerNorm over D=1024, one block per token ----------------
__global__ __launch_bounds__(256) void layernorm_kernel(
        const float* __restrict__ x, const float* __restrict__ g,
        const float* __restrict__ b, float* __restrict__ u) {
    const int t = blockIdx.x;
    const int tid = threadIdx.x;
    const float4 xv = ((const float4*)(x + (size_t)t * DMODEL))[tid];
    float s = xv.x + xv.y + xv.z + xv.w;
    float q = xv.x*xv.x + xv.y*xv.y + xv.z*xv.z + xv.w*xv.w;
    #pragma unroll
    for (int off = 32; off >= 1; off >>= 1) {
        s += __shfl_xor(s, off);
        q += __shfl_xor(q, off);
    }
    __shared__ float red[8];
    if ((tid & 63) == 0) { red[tid >> 6] = s; red[4 + (tid >> 6)] = q; }
    __syncthreads();
    s = red[0] + red[1] + red[2] + red[3];
    q = red[4] + red[5] + red[6] + red[7];
    const float mu   = s * (1.f / DMODEL);
    const float var  = q * (1.f / DMODEL) - mu * mu;
    const float rstd = rsqrtf(var + LN_EPS);
    const float4 gv = ((const float4*)g)[tid];
    const float4 bv = ((const float4*)b)[tid];
    float4 o;
    o.x = (xv.x - mu) * rstd * gv.x + bv.x;
    o.y = (xv.y - mu) * rstd * gv.y + bv.y;
    o.z = (xv.z - mu) * rstd * gv.z + bv.z;
    o.w = (xv.w - mu) * rstd * gv.w + bv.w;
    ((float4*)(u + (size_t)t * DMODEL))[tid] = o;
}

// ---------------- generic fp32 GEMM, C[M,N] = A[M,K] * B[N,K]^T ----------------
enum { E_NONE = 0, E_BIAS_POS = 1, E_BIAS_SOFTPLUS = 2, E_RESADD = 3 };

template<int EPI>
__global__ __launch_bounds__(256) void gemm_nt(
        const float* __restrict__ A, int lda,
        const float* __restrict__ B, int ldb,
        float* __restrict__ C, int M, int N, int Ksub,
        const float* __restrict__ bias, const float* __restrict__ aux) {
    __shared__ float As[16][64];
    __shared__ float Bs[16][64];
    const int tid = threadIdx.x;
    const int m0 = blockIdx.x * 64;
    const int n0 = blockIdx.y * 64;
    const int koff = blockIdx.z * Ksub;
    C += (size_t)blockIdx.z * M * N;

    const int lrow = tid >> 2;   // 0..63
    const int kq   = tid & 3;    // 0..3
    const float* aptr = A + (size_t)(m0 + lrow) * lda + koff + kq * 4;
    const bool   bok  = (n0 + lrow) < N;
    const float* bptr = B + (size_t)(n0 + lrow) * ldb + koff + kq * 4;

    float acc[4][4] = {{0.f}};
    for (int k0 = 0; k0 < Ksub; k0 += 16) {
        const float4 av = *(const float4*)(aptr + k0);
        const float4 bv = bok ? *(const float4*)(bptr + k0) : make_float4(0.f, 0.f, 0.f, 0.f);
        __syncthreads();
        As[kq*4+0][lrow] = av.x; As[kq*4+1][lrow] = av.y;
        As[kq*4+2][lrow] = av.z; As[kq*4+3][lrow] = av.w;
        Bs[kq*4+0][lrow] = bv.x; Bs[kq*4+1][lrow] = bv.y;
        Bs[kq*4+2][lrow] = bv.z; Bs[kq*4+3][lrow] = bv.w;
        __syncthreads();
        #pragma unroll
        for (int kk = 0; kk < 16; ++kk) {
            const float4 a = *(const float4*)&As[kk][(tid >> 4) << 2];
            const float4 b = *(const float4*)&Bs[kk][(tid & 15) << 2];
            const float aa[4] = {a.x, a.y, a.z, a.w};
            const float bb[4] = {b.x, b.y, b.z, b.w};
            #pragma unroll
            for (int i = 0; i < 4; ++i)
                #pragma unroll
                for (int j = 0; j < 4; ++j)
                    acc[i][j] = fmaf(aa[i], bb[j], acc[i][j]);
        }
    }

    const int mb = m0 + ((tid >> 4) << 2);
    const int nb = n0 + ((tid & 15) << 2);
    if (nb >= N) return;
    #pragma unroll
    for (int i = 0; i < 4; ++i) {
        const int m = mb + i;
        float4 v = make_float4(acc[i][0], acc[i][1], acc[i][2], acc[i][3]);
        float* cp = C + (size_t)m * N + nb;
        if (EPI == E_BIAS_POS) {
            const float4 bz = *(const float4*)(bias + nb);
            const float4 pz = *(const float4*)(aux + (size_t)(m % LTOK) * DMODEL + nb);
            v.x += bz.x + pz.x; v.y += bz.y + pz.y; v.z += bz.z + pz.z; v.w += bz.w + pz.w;
        } else if (EPI == E_BIAS_SOFTPLUS) {
            const float4 bz = *(const float4*)(bias + nb);
            v.x += bz.x; v.y += bz.y; v.z += bz.z; v.w += bz.w;
            v.x = (v.x > 20.f) ? v.x : log1pf(__expf(v.x));
            v.y = (v.y > 20.f) ? v.y : log1pf(__expf(v.y));
            v.z = (v.z > 20.f) ? v.z : log1pf(__expf(v.z));
            v.w = (v.w > 20.f) ? v.w : log1pf(__expf(v.w));
        } else if (EPI == E_RESADD) {
            const float4 r = *(const float4*)cp;
            v.x += r.x; v.y += r.y; v.z += r.z; v.w += r.w;
        }
        *(float4*)cp = v;
    }
}

// ---------------- causal depthwise conv1d (DC=4) + silu ----------------
__global__ void conv1d_silu_kernel(const float* __restrict__ xz,
                                   const float* __restrict__ wc,
                                   const float* __restrict__ bc,
                                   float* __restrict__ xc) {
    int idx = blockIdx.x * blockDim.x + threadIdx.x;
    if (idx >= NTOK * DI) return;
    const int t = idx >> 11;          // DI = 2048
    const int e = idx & (DI - 1);
    const int l = t % LTOK;
    const float4 w = *(const float4*)(wc + e * DC);
    const float* xp = xz + (size_t)t * (2*DI) + e;
    float acc = bc[e] + w.w * xp[0];
    if (l >= 1) acc += w.z * xp[-(2*DI)];
    if (l >= 2) acc += w.y * xp[-2*(2*DI)];
    if (l >= 3) acc += w.x * xp[-3*(2*DI)];
    xc[idx] = acc * sigmoidf_(acc);
}

// ================= chunked parallel selective scan =================
// Thread = (b, e) with h[16] in registers; B/C rows staged in LDS (broadcast
// float4 reads, conflict-free). L split into NCH chunks of LC.
// Pass 1: per chunk, local scan from h=0 -> F (final local state) + sum(dt).
//         (decay product over chunk = exp(A_s * sum_dt) -- factorization)
// Pass 2: tiny sequential combine across chunks -> per-chunk incoming state H.
// Pass 3: replay chunk from H, compute y = sum_s h*C fused with D*xc, silu(z).

__global__ __launch_bounds__(256) void scan_pass1(
        const float* __restrict__ dt, const float* __restrict__ xc,
        const float* __restrict__ dbc, const float* __restrict__ Alog,
        float* __restrict__ Fst, float* __restrict__ sdt) {
    const int tid = threadIdx.x;
    const int e  = blockIdx.x * 256 + tid;
    const int c  = blockIdx.y;
    const int b  = blockIdx.z;
    const int l0 = c * LC;
    const size_t tb = (size_t)b * LTOK + l0;

    __shared__ float Bs[LC][16];
    for (int idx = tid; idx < LC * 16; idx += 256) {
        const int row = idx >> 4, s = idx & 15;
        Bs[row][s] = dbc[(tb + row) * 96 + 64 + s];
    }

    float Aval[DSTATE];
    {
        const float* ap = Alog + (size_t)e * DSTATE;
        #pragma unroll
        for (int s = 0; s < DSTATE; ++s) Aval[s] = -__expf(ap[s]);
    }
    __syncthreads();

    const float* dtp = dt + tb * DI + e;
    const float* xcp = xc + tb * DI + e;
    float h[DSTATE];
    #pragma unroll
    for (int s = 0; s < DSTATE; ++s) h[s] = 0.f;
    float sum_dt = 0.f;

    float dtv = dtp[0], xcv = xcp[0];
    for (int l = 0; l < LC; ++l) {
        float dtn = 0.f, xcn = 0.f;
        if (l + 1 < LC) { dtn = dtp[(size_t)(l+1) * DI]; xcn = xcp[(size_t)(l+1) * DI]; }
        sum_dt += dtv;
        const float dx = dtv * xcv;
        const float4* brow = (const float4*)&Bs[l][0];
        const float4 b0 = brow[0], b1 = brow[1], b2 = brow[2], b3 = brow[3];
        const float bb[16] = {b0.x,b0.y,b0.z,b0.w, b1.x,b1.y,b1.z,b1.w,
                              b2.x,b2.y,b2.z,b2.w, b3.x,b3.y,b3.z,b3.w};
        #pragma unroll
        for (int s = 0; s < DSTATE; ++s)
            h[s] = fmaf(__expf(dtv * Aval[s]), h[s], dx * bb[s]);
        dtv = dtn; xcv = xcn;
    }

    float4* Fp = (float4*)(Fst + ((((size_t)b * NCH + c) * DI) + e) * DSTATE);
    #pragma unroll
    for (int q = 0; q < 4; ++q)
        Fp[q] = make_float4(h[q*4+0], h[q*4+1], h[q*4+2], h[q*4+3]);
    sdt[((size_t)b * NCH + c) * DI + e] = sum_dt;
}

__global__ __launch_bounds__(256) void scan_pass2(
        const float* __restrict__ Fst, const float* __restrict__ sdt,
        const float* __restrict__ Alog, float* __restrict__ Hst) {
    const int idx = blockIdx.x * 256 + threadIdx.x;   // [B*DI*DSTATE)
    const int s = idx & 15;
    const int e = (idx >> 4) & (DI - 1);
    const int b = idx >> 15;
    const float Aval = -__expf(Alog[(size_t)e * DSTATE + s]);
    float h = 0.f;
    for (int c = 0; c < NCH; ++c) {
        const size_t base = ((size_t)b * NCH + c) * DI + e;
        Hst[base * DSTATE + s] = h;
        h = fmaf(__expf(Aval * sdt[base]), h, Fst[base * DSTATE + s]);
    }
}

__global__ __launch_bounds__(256) void scan_pass3(
        const float* __restrict__ dt, const float* __restrict__ xc,
        const float* __restrict__ dbc, const float* __restrict__ xz,
        const float* __restrict__ Alog, const float* __restrict__ Dp,
        const float* __restrict__ Hst, float* __restrict__ y) {
    const int tid = threadIdx.x;
    const int e  = blockIdx.x * 256 + tid;
    const int c  = blockIdx.y;
    const int b  = blockIdx.z;
    const int l0 = c * LC;
    const size_t tb = (size_t)b * LTOK + l0;

    __shared__ float BCs[LC][32];   // cols 0..15 = B, 16..31 = C
    for (int idx = tid; idx < LC * 32; idx += 256) {
        const int row = idx >> 5, col = idx & 31;
        BCs[row][col] = dbc[(tb + row) * 96 + 64 + col];
    }

    float Aval[DSTATE];
    {
        const float* ap = Alog + (size_t)e * DSTATE;
        #pragma unroll
        for (int s = 0; s < DSTATE; ++s) Aval[s] = -__expf(ap[s]);
    }
    const float Dv = Dp[e];

    float h[DSTATE];
    {
        const float4* Hp = (const float4*)(Hst + ((((size_t)b * NCH + c) * DI) + e) * DSTATE);
        #pragma unroll
        for (int q = 0; q < 4; ++q) {
            const float4 hv = Hp[q];
            h[q*4+0] = hv.x; h[q*4+1] = hv.y; h[q*4+2] = hv.z; h[q*4+3] = hv.w;
        }
    }
    __syncthreads();

    const float* dtp = dt + tb * DI + e;
    const float* xcp = xc + tb * DI + e;
    const float* zp  = xz + tb * (2*DI) + DI + e;
    float* yp = y + tb * DI + e;

    float dtv = dtp[0], xcv = xcp[0], zv = zp[0];
    for (int l = 0; l < LC; ++l) {
        float dtn = 0.f, xcn = 0.f, zn = 0.f;
        if (l + 1 < LC) {
            dtn = dtp[(size_t)(l+1) * DI];
            xcn = xcp[(size_t)(l+1) * DI];
            zn  = zp[(size_t)(l+1) * (2*DI)];
        }
        const float dx = dtv * xcv;
        const float4* brow = (const float4*)&BCs[l][0];
        const float4 b0 = brow[0], b1 = brow[1], b2 = brow[2], b3 = brow[3];
        const float4 c0 = brow[4], c1 = brow[5], c2 = brow[6], c3 = brow[7];
        const float bb[16] = {b0.x,b0.y,b0.z,b0.w, b1.x,b1.y,b1.z,b1.w,
                              b2.x,b2.y,b2.z,b2.w, b3.x,b3.y,b3.z,b3.w};
        const float cc[16] = {c0.x,c0.y,c0.z,c0.w, c1.x,c1.y,c1.z,c1.w,
                              c2.x,c2.y,c2.z,c2.w, c3.x,c3.y,c3.z,c3.w};
        float yv = 0.f;
        #pragma unroll
        for (int s = 0; s < DSTATE; ++s) {
            h[s] = fmaf(__expf(dtv * Aval[s]), h[s], dx * bb[s]);
            yv = fmaf(h[s], cc[s], yv);
        }
        yp[(size_t)l * DI] = (yv + Dv * xcv) * (zv * sigmoidf_(zv));
        dtv = dtn; xcv = xcn; zv = zn;
    }
}

// ---------------- split-K reduce (8 partials) ----------------
__global__ void reduce8_kernel(const float* __restrict__ part, float* __restrict__ out, int n) {
    int i = blockIdx.x * blockDim.x + threadIdx.x;
    if (i >= n) return;
    float s = 0.f;
    #pragma unroll
    for (int z = 0; z < 8; ++z) s += part[(size_t)z * n + i];
    out[i] = s;
}

extern "C" void kernel_launch(void* const* d_in, const int* in_sizes, int n_in,
                              void* d_out, int out_size, void* d_ws, size_t ws_size,
                              hipStream_t stream) {
    const float* x       = (const float*)d_in[0];
    const float* patch_w = (const float*)d_in[1];
    const float* patch_b = (const float*)d_in[2];
    const float* pos     = (const float*)d_in[3];
    const float* ln_g    = (const float*)d_in[4];
    const float* ln_b    = (const float*)d_in[5];
    const float* in_w    = (const float*)d_in[6];
    const float* conv_w  = (const float*)d_in[7];
    const float* conv_b  = (const float*)d_in[8];
    const float* xproj_w = (const float*)d_in[9];
    const float* dt_w    = (const float*)d_in[10];
    const float* dt_b    = (const float*)d_in[11];
    const float* A_log   = (const float*)d_in[12];
    const float* D_par   = (const float*)d_in[13];
    const float* out_w   = (const float*)d_in[14];

    float* tok = (float*)d_out;                     // running residual stream [1152, 1024]
    float* ws  = (float*)d_ws;
    float* Xcol = ws;  ws += (size_t)NTOK * KPATCH;
    float* u    = ws;  ws += (size_t)NTOK * DMODEL;
    float* xz   = ws;  ws += (size_t)NTOK * 2 * DI;
    float* xc   = ws;  ws += (size_t)NTOK * DI;
    float* dbcP = ws;  ws += (size_t)8 * NTOK * 96;
    float* dbc  = ws;  ws += (size_t)NTOK * 96;
    float* dtb  = ws;  ws += (size_t)NTOK * DI;
    float* yb   = ws;  ws += (size_t)NTOK * DI;
    float* Fst  = ws;  ws += (size_t)BATCH * NCH * DI * DSTATE;   // 4 MB
    float* Hst  = ws;  ws += (size_t)BATCH * NCH * DI * DSTATE;   // 4 MB
    float* sdt  = ws;  ws += (size_t)BATCH * NCH * DI;            // 0.25 MB

    // ---- patch embed: tok = im2col(x) @ patch_w^T + patch_b + pos ----
    im2col_kernel<<<(NTOK*KPATCH + 255)/256, 256, 0, stream>>>(x, Xcol);
    gemm_nt<E_BIAS_POS><<<dim3(NTOK/64, DMODEL/64), 256, 0, stream>>>(
        Xcol, KPATCH, patch_w, KPATCH, tok, NTOK, DMODEL, KPATCH, patch_b, pos);

    for (int layer = 0; layer < NLAYERS; ++layer) {
        const float* Wg  = ln_g    + (size_t)layer * DMODEL;
        const float* Wb  = ln_b    + (size_t)layer * DMODEL;
        const float* Win = in_w    + (size_t)layer * 2 * DI * DMODEL;
        const float* Wc  = conv_w  + (size_t)layer * DI * DC;
        const float* Bc  = conv_b  + (size_t)layer * DI;
        const float* Wxp = xproj_w + (size_t)layer * 96 * DI;
        const float* Wdt = dt_w    + (size_t)layer * DI * DTR;
        const float* Bdt = dt_b    + (size_t)layer * DI;
        const float* Al  = A_log   + (size_t)layer * DI * DSTATE;
        const float* Dd  = D_par   + (size_t)layer * DI;
        const float* Wo  = out_w   + (size_t)layer * DMODEL * DI;

        // u = LN(tok)
        layernorm_kernel<<<NTOK, 256, 0, stream>>>(tok, Wg, Wb, u);
        // xz = u @ Win^T   [1152, 4096]
        gemm_nt<E_NONE><<<dim3(NTOK/64, (2*DI)/64), 256, 0, stream>>>(
            u, DMODEL, Win, DMODEL, xz, NTOK, 2*DI, DMODEL, nullptr, nullptr);
        // xc = silu(causal_conv(xi) + bc)
        conv1d_silu_kernel<<<(NTOK*DI + 255)/256, 256, 0, stream>>>(xz, Wc, Bc, xc);
        // dbc = xc @ Wxp^T  [1152, 96], split-K=8 (deterministic reduce)
        gemm_nt<E_NONE><<<dim3(NTOK/64, 2, 8), 256, 0, stream>>>(
            xc, DI, Wxp, DI, dbcP, NTOK, 96, DI/8, nullptr, nullptr);
        reduce8_kernel<<<(NTOK*96 + 255)/256, 256, 0, stream>>>(dbcP, dbc, NTOK*96);
        // dt = softplus(dbc[:, :64] @ Wdt^T + bdt)  [1152, 2048]
        gemm_nt<E_BIAS_SOFTPLUS><<<dim3(NTOK/64, DI/64), 256, 0, stream>>>(
            dbc, 96, Wdt, DTR, dtb, NTOK, DI, DTR, Bdt, nullptr);
        // chunked parallel selective scan + D*xc + silu(z) gate -> yb
        scan_pass1<<<dim3(DI/256, NCH, BATCH), 256, 0, stream>>>(
            dtb, xc, dbc, Al, Fst, sdt);
        scan_pass2<<<(BATCH*DI*DSTATE)/256, 256, 0, stream>>>(Fst, sdt, Al, Hst);
        scan_pass3<<<dim3(DI/256, NCH, BATCH), 256, 0, stream>>>(
            dtb, xc, dbc, xz, Al, Dd, Hst, yb);
        // tok += yb @ Wo^T
        gemm_nt<E_RESADD><<<dim3(NTOK/64, DMODEL/64), 256, 0, stream>>>(
            yb, DI, Wo, DI, tok, NTOK, DMODEL, DI, nullptr, nullptr);
    }
}

// Round 3
// 4659.951 us; speedup vs baseline: 4.0510x; 2.1175x over previous
//
#include <hip/hip_runtime.h>
#include <hip/hip_bf16.h>
#include <math.h>

// ---- problem constants (from reference) ----
#define PATCH   16
#define HIMG    384
#define WIMG    384
#define DMODEL  1024
#define NLAYERS 24
#define DI      2048
#define DSTATE  16
#define DTR     64
#define DC      4
#define LN_EPS  1e-5f
#define BATCH   2
#define GRIDTOK 24                 // 384/16
#define LTOK    (GRIDTOK*GRIDTOK)  // 576
#define NTOK    (BATCH*LTOK)       // 1152
#define KPATCH  (3*PATCH*PATCH)    // 768
#define NCH     16                 // scan chunks
#define LC      (LTOK/NCH)         // 36 steps per chunk

typedef __attribute__((ext_vector_type(8))) short short8;
typedef __attribute__((ext_vector_type(4))) float f32x4;

__device__ __forceinline__ float sigmoidf_(float v) { return 1.f / (1.f + __expf(-v)); }
__device__ __forceinline__ unsigned short f2bf(float f) {
    __hip_bfloat16 h = __float2bfloat16(f);   // RNE
    return *(unsigned short*)&h;
}

// ---------------- im2col for the 16x16/stride-16 patch conv ----------------
__global__ void im2col_kernel(const float* __restrict__ x, float* __restrict__ xcol) {
    int idx = blockIdx.x * blockDim.x + threadIdx.x;
    if (idx >= NTOK * KPATCH) return;
    int t = idx / KPATCH, k = idx % KPATCH;
    int b = t / LTOK, hw = t % LTOK;
    int h = hw / GRIDTOK, w = hw % GRIDTOK;
    int c = k / (PATCH*PATCH), r = k % (PATCH*PATCH);
    int i = r / PATCH, j = r % PATCH;
    xcol[idx] = x[(((size_t)(b*3 + c)*HIMG) + h*PATCH + i)*WIMG + w*PATCH + j];
}

// ---------------- LayerNorm over D=1024 -> bf16 output ----------------
__global__ __launch_bounds__(256) void layernorm_kernel(
        const float* __restrict__ x, const float* __restrict__ g,
        const float* __restrict__ b, unsigned short* __restrict__ u) {
    const int t = blockIdx.x;
    const int tid = threadIdx.x;
    const float4 xv = ((const float4*)(x + (size_t)t * DMODEL))[tid];
    float s = xv.x + xv.y + xv.z + xv.w;
    float q = xv.x*xv.x + xv.y*xv.y + xv.z*xv.z + xv.w*xv.w;
    #pragma unroll
    for (int off = 32; off >= 1; off >>= 1) {
        s += __shfl_xor(s, off);
        q += __shfl_xor(q, off);
    }
    __shared__ float red[8];
    if ((tid & 63) == 0) { red[tid >> 6] = s; red[4 + (tid >> 6)] = q; }
    __syncthreads();
    s = red[0] + red[1] + red[2] + red[3];
    q = red[4] + red[5] + red[6] + red[7];
    const float mu   = s * (1.f / DMODEL);
    const float var  = q * (1.f / DMODEL) - mu * mu;
    const float rstd = rsqrtf(var + LN_EPS);
    const float4 gv = ((const float4*)g)[tid];
    const float4 bv = ((const float4*)b)[tid];
    ushort4 o;
    o.x = f2bf((xv.x - mu) * rstd * gv.x + bv.x);
    o.y = f2bf((xv.y - mu) * rstd * gv.y + bv.y);
    o.z = f2bf((xv.z - mu) * rstd * gv.z + bv.z);
    o.w = f2bf((xv.w - mu) * rstd * gv.w + bv.w);
    ((ushort4*)(u + (size_t)t * DMODEL))[tid] = o;
}

// ================ bf16 MFMA GEMM: C[M,N] = A_bf16[M,K] * B_f32[N,K]^T ================
// 128x128 tile, BK=64, 256 threads = 4 waves of 64x64. B converted fp32->bf16
// during LDS staging. XOR-swizzled LDS (slot ^ (row&7)) -> 2-way conflicts only.
// SPLITK=1: grid.z partials written to C + z*M*N (deterministic reduce after).
template<int SPLITK>
__global__ __launch_bounds__(256) void gemm_mfma_bt(
        const unsigned short* __restrict__ A, int lda,
        const float* __restrict__ B, int ldb,
        float* __restrict__ C, int M, int N, int Ksub) {
    __shared__ unsigned short As[128 * 64];
    __shared__ unsigned short Bs[128 * 64];
    const int tid = threadIdx.x;
    const int m0 = blockIdx.x * 128;
    const int n0 = blockIdx.y * 128;
    const int koff = SPLITK ? blockIdx.z * Ksub : 0;
    if (SPLITK) C += (size_t)blockIdx.z * M * N;

    const int lane = tid & 63;
    const int wid  = tid >> 6;
    const int wm = (wid >> 1) * 64;     // wave row offset in tile
    const int wn = (wid & 1) * 64;      // wave col offset in tile
    const int fr = lane & 15;           // fragment row/col
    const int cb = lane >> 4;           // k-slice group

    const int srow = tid >> 3;          // 0..31 staging row base
    const int skc  = tid & 7;           // 0..7  staging k-chunk (8 elems)

    f32x4 acc[4][4];
    #pragma unroll
    for (int i = 0; i < 4; ++i)
        #pragma unroll
        for (int j = 0; j < 4; ++j) acc[i][j] = (f32x4){0.f, 0.f, 0.f, 0.f};

    uint4  areg[4];
    float4 breg[4][2];

    const int nk = Ksub / 64;
    // prologue: load K-tile 0
    #pragma unroll
    for (int i = 0; i < 4; ++i) {
        const int r = srow + 32 * i;
        areg[i] = *(const uint4*)(A + (size_t)(m0 + r) * lda + koff + skc * 8);
        const float* bp = B + (size_t)(n0 + r) * ldb + koff + skc * 8;
        breg[i][0] = *(const float4*)bp;
        breg[i][1] = *(const float4*)(bp + 4);
    }

    for (int ks = 0; ks < nk; ++ks) {
        __syncthreads();   // previous iteration's LDS reads complete
        #pragma unroll
        for (int i = 0; i < 4; ++i) {
            const int r = srow + 32 * i;
            const int idx = r * 64 + ((skc ^ (r & 7)) << 3);
            *(uint4*)&As[idx] = areg[i];
            const float* bf = (const float*)&breg[i][0];
            short8 hv;
            #pragma unroll
            for (int j = 0; j < 8; ++j) hv[j] = (short)f2bf(bf[j]);
            *(short8*)&Bs[idx] = hv;
        }
        __syncthreads();
        if (ks + 1 < nk) {
            const int k1 = koff + (ks + 1) * 64;
            #pragma unroll
            for (int i = 0; i < 4; ++i) {
                const int r = srow + 32 * i;
                areg[i] = *(const uint4*)(A + (size_t)(m0 + r) * lda + k1 + skc * 8);
                const float* bp = B + (size_t)(n0 + r) * ldb + k1 + skc * 8;
                breg[i][0] = *(const float4*)bp;
                breg[i][1] = *(const float4*)(bp + 4);
            }
        }
        #pragma unroll
        for (int kk = 0; kk < 2; ++kk) {
            short8 af[4], bfr[4];
            #pragma unroll
            for (int mi = 0; mi < 4; ++mi) {
                const int row = wm + mi * 16 + fr;
                af[mi] = *(const short8*)&As[row * 64 + (((kk * 4 + cb) ^ (row & 7)) << 3)];
            }
            #pragma unroll
            for (int ni = 0; ni < 4; ++ni) {
                const int row = wn + ni * 16 + fr;
                bfr[ni] = *(const short8*)&Bs[row * 64 + (((kk * 4 + cb) ^ (row & 7)) << 3)];
            }
            #pragma unroll
            for (int mi = 0; mi < 4; ++mi)
                #pragma unroll
                for (int ni = 0; ni < 4; ++ni)
                    acc[mi][ni] = __builtin_amdgcn_mfma_f32_16x16x32_bf16(
                        af[mi], bfr[ni], acc[mi][ni], 0, 0, 0);
        }
    }

    // C/D mapping (m89-verified): col = lane&15, row = (lane>>4)*4 + reg
    #pragma unroll
    for (int mi = 0; mi < 4; ++mi) {
        const int rbase = m0 + wm + mi * 16 + cb * 4;
        #pragma unroll
        for (int ni = 0; ni < 4; ++ni) {
            const int col = n0 + wn + ni * 16 + fr;
            #pragma unroll
            for (int j = 0; j < 4; ++j)
                C[(size_t)(rbase + j) * N + col] = acc[mi][ni][j];
        }
    }
}

// tok += sum of 4 split-K partials (out_proj epilogue)
__global__ void reduce4_resadd_kernel(const float* __restrict__ part,
                                      float* __restrict__ tok, int n4) {
    int i = blockIdx.x * blockDim.x + threadIdx.x;
    if (i >= n4) return;
    float4 v = ((const float4*)part)[i];
    const float4 p1 = ((const float4*)part)[(size_t)1 * n4 + i];
    const float4 p2 = ((const float4*)part)[(size_t)2 * n4 + i];
    const float4 p3 = ((const float4*)part)[(size_t)3 * n4 + i];
    float4 t = ((float4*)tok)[i];
    t.x += v.x + p1.x + p2.x + p3.x;
    t.y += v.y + p1.y + p2.y + p3.y;
    t.z += v.z + p1.z + p2.z + p3.z;
    t.w += v.w + p1.w + p2.w + p3.w;
    ((float4*)tok)[i] = t;
}

// ---------------- generic fp32 GEMM (small ops), C[M,N] = A[M,K] * B[N,K]^T ----------------
enum { E_NONE = 0, E_BIAS_POS = 1, E_BIAS_SOFTPLUS = 2 };

template<int EPI>
__global__ __launch_bounds__(256) void gemm_nt(
        const float* __restrict__ A, int lda,
        const float* __restrict__ B, int ldb,
        float* __restrict__ C, int M, int N, int Ksub,
        const float* __restrict__ bias, const float* __restrict__ aux) {
    __shared__ float As[16][64];
    __shared__ float Bs[16][64];
    const int tid = threadIdx.x;
    const int m0 = blockIdx.x * 64;
    const int n0 = blockIdx.y * 64;
    const int koff = blockIdx.z * Ksub;
    C += (size_t)blockIdx.z * M * N;

    const int lrow = tid >> 2;
    const int kq   = tid & 3;
    const float* aptr = A + (size_t)(m0 + lrow) * lda + koff + kq * 4;
    const bool   bok  = (n0 + lrow) < N;
    const float* bptr = B + (size_t)(n0 + lrow) * ldb + koff + kq * 4;

    float acc[4][4] = {{0.f}};
    for (int k0 = 0; k0 < Ksub; k0 += 16) {
        const float4 av = *(const float4*)(aptr + k0);
        const float4 bv = bok ? *(const float4*)(bptr + k0) : make_float4(0.f, 0.f, 0.f, 0.f);
        __syncthreads();
        As[kq*4+0][lrow] = av.x; As[kq*4+1][lrow] = av.y;
        As[kq*4+2][lrow] = av.z; As[kq*4+3][lrow] = av.w;
        Bs[kq*4+0][lrow] = bv.x; Bs[kq*4+1][lrow] = bv.y;
        Bs[kq*4+2][lrow] = bv.z; Bs[kq*4+3][lrow] = bv.w;
        __syncthreads();
        #pragma unroll
        for (int kk = 0; kk < 16; ++kk) {
            const float4 a = *(const float4*)&As[kk][(tid >> 4) << 2];
            const float4 b = *(const float4*)&Bs[kk][(tid & 15) << 2];
            const float aa[4] = {a.x, a.y, a.z, a.w};
            const float bb[4] = {b.x, b.y, b.z, b.w};
            #pragma unroll
            for (int i = 0; i < 4; ++i)
                #pragma unroll
                for (int j = 0; j < 4; ++j)
                    acc[i][j] = fmaf(aa[i], bb[j], acc[i][j]);
        }
    }

    const int mb = m0 + ((tid >> 4) << 2);
    const int nb = n0 + ((tid & 15) << 2);
    if (nb >= N) return;
    #pragma unroll
    for (int i = 0; i < 4; ++i) {
        const int m = mb + i;
        float4 v = make_float4(acc[i][0], acc[i][1], acc[i][2], acc[i][3]);
        float* cp = C + (size_t)m * N + nb;
        if (EPI == E_BIAS_POS) {
            const float4 bz = *(const float4*)(bias + nb);
            const float4 pz = *(const float4*)(aux + (size_t)(m % LTOK) * DMODEL + nb);
            v.x += bz.x + pz.x; v.y += bz.y + pz.y; v.z += bz.z + pz.z; v.w += bz.w + pz.w;
        } else if (EPI == E_BIAS_SOFTPLUS) {
            const float4 bz = *(const float4*)(bias + nb);
            v.x += bz.x; v.y += bz.y; v.z += bz.z; v.w += bz.w;
            v.x = (v.x > 20.f) ? v.x : log1pf(__expf(v.x));
            v.y = (v.y > 20.f) ? v.y : log1pf(__expf(v.y));
            v.z = (v.z > 20.f) ? v.z : log1pf(__expf(v.z));
            v.w = (v.w > 20.f) ? v.w : log1pf(__expf(v.w));
        }
        *(float4*)cp = v;
    }
}

// ---------------- causal depthwise conv1d (DC=4) + silu ----------------
__global__ void conv1d_silu_kernel(const float* __restrict__ xz,
                                   const float* __restrict__ wc,
                                   const float* __restrict__ bc,
                                   float* __restrict__ xc) {
    int idx = blockIdx.x * blockDim.x + threadIdx.x;
    if (idx >= NTOK * DI) return;
    const int t = idx >> 11;
    const int e = idx & (DI - 1);
    const int l = t % LTOK;
    const float4 w = *(const float4*)(wc + e * DC);
    const float* xp = xz + (size_t)t * (2*DI) + e;
    float acc = bc[e] + w.w * xp[0];
    if (l >= 1) acc += w.z * xp[-(2*DI)];
    if (l >= 2) acc += w.y * xp[-2*(2*DI)];
    if (l >= 3) acc += w.x * xp[-3*(2*DI)];
    xc[idx] = acc * sigmoidf_(acc);
}

// ================= chunked parallel selective scan =================
__global__ __launch_bounds__(256) void scan_pass1(
        const float* __restrict__ dt, const float* __restrict__ xc,
        const float* __restrict__ dbc, const float* __restrict__ Alog,
        float* __restrict__ Fst, float* __restrict__ sdt) {
    const int tid = threadIdx.x;
    const int e  = blockIdx.x * 256 + tid;
    const int c  = blockIdx.y;
    const int b  = blockIdx.z;
    const int l0 = c * LC;
    const size_t tb = (size_t)b * LTOK + l0;

    __shared__ float Bs[LC][16];
    for (int idx = tid; idx < LC * 16; idx += 256) {
        const int row = idx >> 4, s = idx & 15;
        Bs[row][s] = dbc[(tb + row) * 96 + 64 + s];
    }

    float Aval[DSTATE];
    {
        const float* ap = Alog + (size_t)e * DSTATE;
        #pragma unroll
        for (int s = 0; s < DSTATE; ++s) Aval[s] = -__expf(ap[s]);
    }
    __syncthreads();

    const float* dtp = dt + tb * DI + e;
    const float* xcp = xc + tb * DI + e;
    float h[DSTATE];
    #pragma unroll
    for (int s = 0; s < DSTATE; ++s) h[s] = 0.f;
    float sum_dt = 0.f;

    float dtv = dtp[0], xcv = xcp[0];
    for (int l = 0; l < LC; ++l) {
        float dtn = 0.f, xcn = 0.f;
        if (l + 1 < LC) { dtn = dtp[(size_t)(l+1) * DI]; xcn = xcp[(size_t)(l+1) * DI]; }
        sum_dt += dtv;
        const float dx = dtv * xcv;
        const float4* brow = (const float4*)&Bs[l][0];
        const float4 b0 = brow[0], b1 = brow[1], b2 = brow[2], b3 = brow[3];
        const float bb[16] = {b0.x,b0.y,b0.z,b0.w, b1.x,b1.y,b1.z,b1.w,
                              b2.x,b2.y,b2.z,b2.w, b3.x,b3.y,b3.z,b3.w};
        #pragma unroll
        for (int s = 0; s < DSTATE; ++s)
            h[s] = fmaf(__expf(dtv * Aval[s]), h[s], dx * bb[s]);
        dtv = dtn; xcv = xcn;
    }

    float4* Fp = (float4*)(Fst + ((((size_t)b * NCH + c) * DI) + e) * DSTATE);
    #pragma unroll
    for (int q = 0; q < 4; ++q)
        Fp[q] = make_float4(h[q*4+0], h[q*4+1], h[q*4+2], h[q*4+3]);
    sdt[((size_t)b * NCH + c) * DI + e] = sum_dt;
}

__global__ __launch_bounds__(256) void scan_pass2(
        const float* __restrict__ Fst, const float* __restrict__ sdt,
        const float* __restrict__ Alog, float* __restrict__ Hst) {
    const int idx = blockIdx.x * 256 + threadIdx.x;
    const int s = idx & 15;
    const int e = (idx >> 4) & (DI - 1);
    const int b = idx >> 15;
    const float Aval = -__expf(Alog[(size_t)e * DSTATE + s]);
    float h = 0.f;
    for (int c = 0; c < NCH; ++c) {
        const size_t base = ((size_t)b * NCH + c) * DI + e;
        Hst[base * DSTATE + s] = h;
        h = fmaf(__expf(Aval * sdt[base]), h, Fst[base * DSTATE + s]);
    }
}

__global__ __launch_bounds__(256) void scan_pass3(
        const float* __restrict__ dt, const float* __restrict__ xc,
        const float* __restrict__ dbc, const float* __restrict__ xz,
        const float* __restrict__ Alog, const float* __restrict__ Dp,
        const float* __restrict__ Hst, unsigned short* __restrict__ y) {
    const int tid = threadIdx.x;
    const int e  = blockIdx.x * 256 + tid;
    const int c  = blockIdx.y;
    const int b  = blockIdx.z;
    const int l0 = c * LC;
    const size_t tb = (size_t)b * LTOK + l0;

    __shared__ float BCs[LC][32];
    for (int idx = tid; idx < LC * 32; idx += 256) {
        const int row = idx >> 5, col = idx & 31;
        BCs[row][col] = dbc[(tb + row) * 96 + 64 + col];
    }

    float Aval[DSTATE];
    {
        const float* ap = Alog + (size_t)e * DSTATE;
        #pragma unroll
        for (int s = 0; s < DSTATE; ++s) Aval[s] = -__expf(ap[s]);
    }
    const float Dv = Dp[e];

    float h[DSTATE];
    {
        const float4* Hp = (const float4*)(Hst + ((((size_t)b * NCH + c) * DI) + e) * DSTATE);
        #pragma unroll
        for (int q = 0; q < 4; ++q) {
            const float4 hv = Hp[q];
            h[q*4+0] = hv.x; h[q*4+1] = hv.y; h[q*4+2] = hv.z; h[q*4+3] = hv.w;
        }
    }
    __syncthreads();

    const float* dtp = dt + tb * DI + e;
    const float* xcp = xc + tb * DI + e;
    const float* zp  = xz + tb * (2*DI) + DI + e;
    unsigned short* yp = y + tb * DI + e;

    float dtv = dtp[0], xcv = xcp[0], zv = zp[0];
    for (int l = 0; l < LC; ++l) {
        float dtn = 0.f, xcn = 0.f, zn = 0.f;
        if (l + 1 < LC) {
            dtn = dtp[(size_t)(l+1) * DI];
            xcn = xcp[(size_t)(l+1) * DI];
            zn  = zp[(size_t)(l+1) * (2*DI)];
        }
        const float dx = dtv * xcv;
        const float4* brow = (const float4*)&BCs[l][0];
        const float4 b0 = brow[0], b1 = brow[1], b2 = brow[2], b3 = brow[3];
        const float4 c0 = brow[4], c1 = brow[5], c2 = brow[6], c3 = brow[7];
        const float bb[16] = {b0.x,b0.y,b0.z,b0.w, b1.x,b1.y,b1.z,b1.w,
                              b2.x,b2.y,b2.z,b2.w, b3.x,b3.y,b3.z,b3.w};
        const float cc[16] = {c0.x,c0.y,c0.z,c0.w, c1.x,c1.y,c1.z,c1.w,
                              c2.x,c2.y,c2.z,c2.w, c3.x,c3.y,c3.z,c3.w};
        float yv = 0.f;
        #pragma unroll
        for (int s = 0; s < DSTATE; ++s) {
            h[s] = fmaf(__expf(dtv * Aval[s]), h[s], dx * bb[s]);
            yv = fmaf(h[s], cc[s], yv);
        }
        yp[(size_t)l * DI] = f2bf((yv + Dv * xcv) * (zv * sigmoidf_(zv)));
        dtv = dtn; xcv = xcn; zv = zn;
    }
}

// ---------------- split-K reduce (8 partials) ----------------
__global__ void reduce8_kernel(const float* __restrict__ part, float* __restrict__ out, int n) {
    int i = blockIdx.x * blockDim.x + threadIdx.x;
    if (i >= n) return;
    float s = 0.f;
    #pragma unroll
    for (int z = 0; z < 8; ++z) s += part[(size_t)z * n + i];
    out[i] = s;
}

extern "C" void kernel_launch(void* const* d_in, const int* in_sizes, int n_in,
                              void* d_out, int out_size, void* d_ws, size_t ws_size,
                              hipStream_t stream) {
    const float* x       = (const float*)d_in[0];
    const float* patch_w = (const float*)d_in[1];
    const float* patch_b = (const float*)d_in[2];
    const float* pos     = (const float*)d_in[3];
    const float* ln_g    = (const float*)d_in[4];
    const float* ln_b    = (const float*)d_in[5];
    const float* in_w    = (const float*)d_in[6];
    const float* conv_w  = (const float*)d_in[7];
    const float* conv_b  = (const float*)d_in[8];
    const float* xproj_w = (const float*)d_in[9];
    const float* dt_w    = (const float*)d_in[10];
    const float* dt_b    = (const float*)d_in[11];
    const float* A_log   = (const float*)d_in[12];
    const float* D_par   = (const float*)d_in[13];
    const float* out_w   = (const float*)d_in[14];

    float* tok = (float*)d_out;                     // residual stream [1152, 1024] fp32
    float* ws  = (float*)d_ws;
    float* Xcol = ws;  ws += (size_t)NTOK * KPATCH;
    unsigned short* u_bf = (unsigned short*)ws; ws += (size_t)NTOK * DMODEL / 2;  // bf16
    float* xz   = ws;  ws += (size_t)NTOK * 2 * DI;   // also reused as split-K partials
    float* xc   = ws;  ws += (size_t)NTOK * DI;
    float* dbcP = ws;  ws += (size_t)8 * NTOK * 96;
    float* dbc  = ws;  ws += (size_t)NTOK * 96;
    float* dtb  = ws;  ws += (size_t)NTOK * DI;
    unsigned short* yb_bf = (unsigned short*)ws; ws += (size_t)NTOK * DI / 2;     // bf16
    float* Fst  = ws;  ws += (size_t)BATCH * NCH * DI * DSTATE;
    float* Hst  = ws;  ws += (size_t)BATCH * NCH * DI * DSTATE;
    float* sdt  = ws;  ws += (size_t)BATCH * NCH * DI;

    // ---- patch embed: tok = im2col(x) @ patch_w^T + patch_b + pos ----
    im2col_kernel<<<(NTOK*KPATCH + 255)/256, 256, 0, stream>>>(x, Xcol);
    gemm_nt<E_BIAS_POS><<<dim3(NTOK/64, DMODEL/64), 256, 0, stream>>>(
        Xcol, KPATCH, patch_w, KPATCH, tok, NTOK, DMODEL, KPATCH, patch_b, pos);

    for (int layer = 0; layer < NLAYERS; ++layer) {
        const float* Wg  = ln_g    + (size_t)layer * DMODEL;
        const float* Wb  = ln_b    + (size_t)layer * DMODEL;
        const float* Win = in_w    + (size_t)layer * 2 * DI * DMODEL;
        const float* Wc  = conv_w  + (size_t)layer * DI * DC;
        const float* Bc  = conv_b  + (size_t)layer * DI;
        const float* Wxp = xproj_w + (size_t)layer * 96 * DI;
        const float* Wdt = dt_w    + (size_t)layer * DI * DTR;
        const float* Bdt = dt_b    + (size_t)layer * DI;
        const float* Al  = A_log   + (size_t)layer * DI * DSTATE;
        const float* Dd  = D_par   + (size_t)layer * DI;
        const float* Wo  = out_w   + (size_t)layer * DMODEL * DI;

        // u = LN(tok) -> bf16
        layernorm_kernel<<<NTOK, 256, 0, stream>>>(tok, Wg, Wb, u_bf);
        // xz = u @ Win^T   [1152, 4096]  (bf16 MFMA)
        gemm_mfma_bt<0><<<dim3(NTOK/128, (2*DI)/128, 1), 256, 0, stream>>>(
            u_bf, DMODEL, Win, DMODEL, xz, NTOK, 2*DI, DMODEL);
        // xc = silu(causal_conv(xi) + bc)
        conv1d_silu_kernel<<<(NTOK*DI + 255)/256, 256, 0, stream>>>(xz, Wc, Bc, xc);
        // dbc = xc @ Wxp^T  [1152, 96], split-K=8 (deterministic reduce)
        gemm_nt<E_NONE><<<dim3(NTOK/64, 2, 8), 256, 0, stream>>>(
            xc, DI, Wxp, DI, dbcP, NTOK, 96, DI/8, nullptr, nullptr);
        reduce8_kernel<<<(NTOK*96 + 255)/256, 256, 0, stream>>>(dbcP, dbc, NTOK*96);
        // dt = softplus(dbc[:, :64] @ Wdt^T + bdt)  [1152, 2048]
        gemm_nt<E_BIAS_SOFTPLUS><<<dim3(NTOK/64, DI/64), 256, 0, stream>>>(
            dbc, 96, Wdt, DTR, dtb, NTOK, DI, DTR, Bdt, nullptr);
        // chunked parallel selective scan + D*xc + silu(z) gate -> yb (bf16)
        scan_pass1<<<dim3(DI/256, NCH, BATCH), 256, 0, stream>>>(
            dtb, xc, dbc, Al, Fst, sdt);
        scan_pass2<<<(BATCH*DI*DSTATE)/256, 256, 0, stream>>>(Fst, sdt, Al, Hst);
        scan_pass3<<<dim3(DI/256, NCH, BATCH), 256, 0, stream>>>(
            dtb, xc, dbc, xz, Al, Dd, Hst, yb_bf);
        // tok += yb @ Wo^T   (bf16 MFMA, split-K=4; partials reuse xz which is
        // dead after scan_pass3; xz size = NTOK*2*DI = 4*NTOK*DMODEL exactly)
        gemm_mfma_bt<1><<<dim3(NTOK/128, DMODEL/128, 4), 256, 0, stream>>>(
            yb_bf, DI, Wo, DI, xz, NTOK, DMODEL, DI/4);
        reduce4_resadd_kernel<<<(NTOK*DMODEL/4 + 255)/256, 256, 0, stream>>>(
            xz, tok, NTOK*DMODEL/4);
    }
}